// Round 15
// baseline (477.685 us; speedup 1.0000x reference)
//
#include <hip/hip_runtime.h>
#include <hip/hip_bf16.h>
#include <math.h>

// Problem constants
constexpr int Bc = 4;      // batch
constexpr int Nc = 784;    // tokens
constexpr int Cc = 512;    // enc channels
constexpr int Tc = 8;      // time
constexpr int Dc = 128;    // proj dim
constexpr int Mc = 785;    // N+1
constexpr int TM1 = 7;     // T-1
constexpr int Pp = 832;    // padded chain dim (13*64)
constexpr int Qrows = 896; // padded q rows
constexpr float TEMP = 0.07f;

typedef __attribute__((ext_vector_type(4))) float f32x4;
typedef __attribute__((ext_vector_type(8))) unsigned short u16x8;
typedef __attribute__((ext_vector_type(8))) __bf16 bf16x8;

__device__ __forceinline__ unsigned short f2bf(float v) {
    __hip_bfloat16 h = __float2bfloat16(v);
    return __builtin_bit_cast(unsigned short, h);
}
__device__ __forceinline__ float bf2f(unsigned short u) {
    return __builtin_bit_cast(float, (unsigned int)u << 16);
}

// ---------------- async 16B global->LDS ----------------
__device__ __forceinline__ void gload16(const void* g, void* l) {
    __builtin_amdgcn_global_load_lds(
        (const __attribute__((address_space(1))) unsigned int*)g,
        (__attribute__((address_space(3))) unsigned int*)l, 16, 0, 0);
}

// ---------------- shared 64x128 double-buffered MFMA K-loop ----------------
template<int LD>
__device__ __forceinline__ void gemm64x128_db(const unsigned short* __restrict__ A,
                                              const unsigned short* __restrict__ BT,
                                              unsigned short* As0, unsigned short* As1,
                                              unsigned short* Bs0, unsigned short* Bs1,
                                              int i0, int j0, int tid, f32x4 (&acc)[4][2])
{
    const int lane = tid & 63, wv = tid >> 6;
    const int g = lane >> 4, lr = lane & 15;
    constexpr int NT = LD / 64;

    #pragma unroll
    for (int q = 0; q < 2; ++q) {
        int s = q * 256 + tid; int r = s >> 3;
        int csw = ((s & 7) << 4) ^ ((r & 7) << 4);
        gload16((const char*)(A + (size_t)(i0 + r) * LD) + csw, As0 + (size_t)s * 8);
    }
    #pragma unroll
    for (int q = 0; q < 4; ++q) {
        int s = q * 256 + tid; int r = s >> 3;
        int csw = ((s & 7) << 4) ^ ((r & 7) << 4);
        gload16((const char*)(BT + (size_t)(j0 + r) * LD) + csw, Bs0 + (size_t)s * 8);
    }
    __syncthreads();

    for (int t = 0; t < NT; ++t) {
        unsigned short* Asc = (t & 1) ? As1 : As0;
        unsigned short* Bsc = (t & 1) ? Bs1 : Bs0;
        if (t + 1 < NT) {
            int k0 = (t + 1) * 64;
            unsigned short* Asn = (t & 1) ? As0 : As1;
            unsigned short* Bsn = (t & 1) ? Bs0 : Bs1;
            #pragma unroll
            for (int q = 0; q < 2; ++q) {
                int s = q * 256 + tid; int r = s >> 3;
                int csw = ((s & 7) << 4) ^ ((r & 7) << 4);
                gload16((const char*)(A + (size_t)(i0 + r) * LD + k0) + csw, Asn + (size_t)s * 8);
            }
            #pragma unroll
            for (int q = 0; q < 4; ++q) {
                int s = q * 256 + tid; int r = s >> 3;
                int csw = ((s & 7) << 4) ^ ((r & 7) << 4);
                gload16((const char*)(BT + (size_t)(j0 + r) * LD + k0) + csw, Bsn + (size_t)s * 8);
            }
        }
        bf16x8 af[2][4], bf[2][2];
        #pragma unroll
        for (int ks = 0; ks < 2; ++ks) {
            #pragma unroll
            for (int m = 0; m < 4; ++m) {
                int r = m * 16 + lr;
                int cb = (ks * 64 + g * 16) ^ ((r & 7) << 4);
                af[ks][m] = __builtin_bit_cast(bf16x8, *(const u16x8*)((const char*)Asc + r * 128 + cb));
            }
            #pragma unroll
            for (int n = 0; n < 2; ++n) {
                int r = wv * 32 + n * 16 + lr;
                int cb = (ks * 64 + g * 16) ^ ((r & 7) << 4);
                bf[ks][n] = __builtin_bit_cast(bf16x8, *(const u16x8*)((const char*)Bsc + r * 128 + cb));
            }
        }
        #pragma unroll
        for (int ks = 0; ks < 2; ++ks)
            #pragma unroll
            for (int m = 0; m < 4; ++m)
                #pragma unroll
                for (int n = 0; n < 2; ++n)
                    acc[m][n] = __builtin_amdgcn_mfma_f32_16x16x32_bf16(af[ks][m], bf[ks][n], acc[m][n], 0, 0, 0);
        __syncthreads();
    }
}

// ---------------- reduction helpers ----------------
__device__ __forceinline__ float blockReduceSum(float v, float* sbuf) {
    #pragma unroll
    for (int off = 32; off; off >>= 1) v += __shfl_down(v, off, 64);
    __syncthreads();
    if ((threadIdx.x & 63) == 0) sbuf[threadIdx.x >> 6] = v;
    __syncthreads();
    return sbuf[0] + sbuf[1] + sbuf[2] + sbuf[3];
}
__device__ __forceinline__ float blockReduceMax(float v, float* sbuf) {
    #pragma unroll
    for (int off = 32; off; off >>= 1) v = fmaxf(v, __shfl_down(v, off, 64));
    __syncthreads();
    if ((threadIdx.x & 63) == 0) sbuf[threadIdx.x >> 6] = v;
    __syncthreads();
    return fmaxf(fmaxf(sbuf[0], sbuf[1]), fmaxf(sbuf[2], sbuf[3]));
}

// ---------------- K1a: pack feats + pack W + zero-init roles ----------------
__global__ __launch_bounds__(256) void k_pack(const float* __restrict__ feats,
                                              const float* __restrict__ Wself,
                                              const float* __restrict__ Wdust,
                                              unsigned int* __restrict__ Abf32,
                                              unsigned short* __restrict__ WTb,
                                              unsigned short* __restrict__ qTb,
                                              float* __restrict__ csR,
                                              float* __restrict__ loss)
{
    __shared__ float lds[Cc * 9];
    int bid = blockIdx.x;
    int tid = threadIdx.x;
    if (bid >= Bc * Nc + 32) {
        int zb = bid - (Bc * Nc + 32);     // 0..7
        if (zb == 0) {
            int n = 6 * Bc * Pp;
            for (int i = tid; i < n; i += 256) csR[i] = 0.f;
            if (tid == 0) *loss = 0.f;
        }
        u16x8 z = {};
        for (int bt = zb * 4; bt < zb * 4 + 4; ++bt) {
            u16x8* dst = (u16x8*)(qTb + ((size_t)bt * Qrows + Nc) * Dc);
            for (int i = tid; i < (Qrows - Nc) * Dc / 8; i += 256) dst[i] = z;
        }
        return;
    }
    if (bid >= Bc * Nc) {
        int pidx = bid - Bc * Nc;
        int which = pidx >> 4;
        int rem = pidx & 15;
        int d0 = (rem >> 3) * 64, c0 = (rem & 7) * 64;
        const float* W = which ? Wdust : Wself;
        unsigned short* O = WTb + (size_t)which * Dc * Cc;
        int tx = tid & 63, ty = tid >> 6;
        #pragma unroll
        for (int y = 0; y < 64; y += 4) lds[(y + ty) * 65 + tx] = W[(size_t)(c0 + y + ty) * Dc + d0 + tx];
        __syncthreads();
        #pragma unroll
        for (int y = 0; y < 64; y += 4) O[(size_t)(d0 + y + ty) * Cc + c0 + tx] = f2bf(lds[tx * 65 + y + ty]);
        return;
    }
    int b = bid / Nc, n = bid % Nc;
    const float* src = feats + (size_t)(b * Nc + n) * Cc * Tc;
    for (int i = tid; i < Cc * Tc; i += 256) lds[(i >> 3) * 9 + (i & 7)] = src[i];
    __syncthreads();
    #pragma unroll
    for (int t = 0; t < Tc; ++t) {
        size_t row = (size_t)(b * Tc + t) * Nc + n;
        float v0 = lds[(2 * tid) * 9 + t];
        float v1 = lds[(2 * tid + 1) * 9 + t];
        unsigned int pk = (unsigned int)f2bf(v0) | ((unsigned int)f2bf(v1) << 16);
        Abf32[row * (Cc / 2) + tid] = pk;
    }
}

// ---------------- K1c: projection GEMM fbuf = Abf @ WT^T + bias ----------------
__global__ __launch_bounds__(256, 3) void k_gemm_proj(const unsigned short* __restrict__ A,
                                                      const unsigned short* __restrict__ BT,
                                                      const float* __restrict__ bias,
                                                      float* __restrict__ Cf)
{
    __shared__ __align__(16) unsigned short As0[64 * 64], As1[64 * 64];
    __shared__ __align__(16) unsigned short Bs0[128 * 64], Bs1[128 * 64];
    const int i0 = blockIdx.x * 64;
    const int tid = threadIdx.x, lane = tid & 63, wv = tid >> 6;
    const int g = lane >> 4, lr = lane & 15;

    f32x4 acc[4][2] = {};
    gemm64x128_db<Cc>(A, BT, As0, As1, Bs0, Bs1, i0, 0, tid, acc);

    #pragma unroll
    for (int n = 0; n < 2; ++n) {
        int col = wv * 32 + n * 16 + lr;
        float bv = bias[col];
        #pragma unroll
        for (int m = 0; m < 4; ++m)
            #pragma unroll
            for (int j = 0; j < 4; ++j) {
                int row = i0 + m * 16 + g * 4 + j;
                Cf[(size_t)row * Dc + col] = acc[m][n][j] + bv;
            }
    }
}

// ---------------- K1e: l2norm rows -> bf16 qTb + fp32 qout (+dust role) ----------------
__global__ __launch_bounds__(256) void k_norm(const float* __restrict__ fbuf,
                                              const float* __restrict__ dust,
                                              const float* __restrict__ Wdust,
                                              const float* __restrict__ bdust,
                                              unsigned short* __restrict__ qTb,
                                              float* __restrict__ qout)
{
    __shared__ float lds[64][129];
    __shared__ float nrm[64][4];
    __shared__ float inv[64];
    __shared__ float red2[2];
    int bt = blockIdx.y;
    int b = bt >> 3, t = bt & 7;
    int tid = threadIdx.x;

    if (blockIdx.x == 13) {
        float* sdust = &lds[0][0];
        for (int i = tid; i < Cc; i += 256) sdust[i] = dust[((size_t)b * Cc + i) * Tc + t];
        __syncthreads();
        float acc = 0.f;
        if (tid < 128) {
            for (int c = 0; c < Cc; ++c) acc += sdust[c] * Wdust[(size_t)c * Dc + tid];
            acc += bdust[tid];
            float s = acc * acc;
            #pragma unroll
            for (int off = 32; off; off >>= 1) s += __shfl_down(s, off, 64);
            if ((tid & 63) == 0) red2[tid >> 6] = s;
        }
        __syncthreads();
        if (tid < 128) {
            float inv0 = 1.f / fmaxf(sqrtf(red2[0] + red2[1]), 1e-12f);
            float qv = acc * inv0;
            qout[(((size_t)b * Dc + tid) * Tc + t) * Mc + Nc] = qv;
        }
        return;
    }

    int n0 = blockIdx.x * 64;
    #pragma unroll
    for (int q = 0; q < 8; ++q) {
        int i = q * 256 + tid;
        int nl = i >> 5, d4 = i & 31;
        f32x4 v = {};
        if (n0 + nl < Nc) v = *(const f32x4*)(fbuf + ((size_t)bt * Nc + n0 + nl) * Dc + d4 * 4);
        *(f32x4*)(&lds[nl][d4 * 4]) = v;
    }
    __syncthreads();
    {
        int r = tid & 63, p = tid >> 6;
        float s = 0.f;
        #pragma unroll
        for (int j = 0; j < 32; ++j) { float v = lds[r][p * 32 + j]; s += v * v; }
        nrm[r][p] = s;
    }
    __syncthreads();
    if (tid < 64) inv[tid] = 1.f / fmaxf(sqrtf(nrm[tid][0] + nrm[tid][1] + nrm[tid][2] + nrm[tid][3]), 1e-12f);
    __syncthreads();
    unsigned int* qT32 = (unsigned int*)(qTb + (size_t)bt * Qrows * Dc);
    #pragma unroll
    for (int q = 0; q < 16; ++q) {
        int i = q * 256 + tid;
        int nl = i >> 6, dp = i & 63;
        if (n0 + nl < Nc) {
            float iv = inv[nl];
            unsigned int pk = (unsigned int)f2bf(lds[nl][2 * dp] * iv)
                            | ((unsigned int)f2bf(lds[nl][2 * dp + 1] * iv) << 16);
            qT32[((size_t)(n0 + nl) * Dc >> 1) + dp] = pk;
        }
    }
    int nl = tid & 63;
    if (n0 + nl < Nc) {
        float iv = inv[nl];
        #pragma unroll
        for (int dd = 0; dd < Dc; dd += 4) {
            int d = dd + (tid >> 6);
            qout[(((size_t)b * Dc + d) * Tc + t) * Mc + n0 + nl] = lds[nl][d] * iv;
        }
    }
}

// ---------------- affinity per-output pipeline (guard-free; statically instantiated) ----------------
__device__ __forceinline__ void aff_process(f32x4 (&acc)[13],
                                            unsigned short* __restrict__ OUT,
                                            float* __restrict__ csFlip,
                                            int r0, int tid, int w, int g, int lr,
                                            float wconst,
                                            unsigned short (*otile)[840],
                                            float (*sred)[4][2],
                                            float* rowsum, float* invZ, float* entP)
{
    constexpr float INVT = 1.0f / TEMP;
    // sweep 1: rowsums (pad tiles contribute exactly 0)
    float rs[4] = {0.f, 0.f, 0.f, 0.f};
    #pragma unroll
    for (int tt = 0; tt < 13; ++tt) {
        #pragma unroll
        for (int j = 0; j < 4; ++j) rs[j] += acc[tt][j];
    }
    #pragma unroll
    for (int off = 1; off <= 8; off <<= 1) {
        #pragma unroll
        for (int j = 0; j < 4; ++j) rs[j] += __shfl_xor(rs[j], off, 64);
    }
    if (lr == 0) {
        #pragma unroll
        for (int j = 0; j < 4; ++j) sred[g * 4 + j][w][0] = rs[j];
    }
    __syncthreads();
    if (tid < 16) {
        float r = sred[tid][0][0] + sred[tid][1][0] + sred[tid][2][0] + sred[tid][3][0];
        rowsum[tid] = r;
        csFlip[r0 + tid] = r;
    }
    __syncthreads();

    // sweep 2: exp-sum + entropy; cache exp into acc
    float invr[4];
    #pragma unroll
    for (int j = 0; j < 4; ++j) invr[j] = 1.0f / rowsum[g * 4 + j];
    const float padc = (w == 3) ? 3.0f : 0.0f;
    float en[4] = {0.f, 0.f, 0.f, 0.f}, es[4] = {0.f, 0.f, 0.f, 0.f};
    #pragma unroll
    for (int tt = 0; tt < 13; ++tt) {
        #pragma unroll
        for (int j = 0; j < 4; ++j) {
            float a = acc[tt][j];
            float e = __expf(a * INVT);
            es[j] += e;
            float p = a * invr[j];
            en[j] -= p * __logf(fmaxf(p, 1e-20f));
            acc[tt][j] = e;
        }
    }
    #pragma unroll
    for (int j = 0; j < 4; ++j) es[j] -= padc;
    #pragma unroll
    for (int off = 1; off <= 8; off <<= 1) {
        #pragma unroll
        for (int j = 0; j < 4; ++j) {
            es[j] += __shfl_xor(es[j], off, 64);
            en[j] += __shfl_xor(en[j], off, 64);
        }
    }
    if (lr == 0) {
        #pragma unroll
        for (int j = 0; j < 4; ++j) { sred[g * 4 + j][w][0] = es[j]; sred[g * 4 + j][w][1] = en[j]; }
    }
    __syncthreads();
    if (tid < 16) {
        float esum = sred[tid][0][0] + sred[tid][1][0] + sred[tid][2][0] + sred[tid][3][0];
        float ent  = sred[tid][0][1] + sred[tid][1][1] + sred[tid][2][1] + sred[tid][3][1];
        float ez  = __expf(ent * wconst * INVT);
        float Z   = esum + ez;
        float iz  = 1.0f / Z;
        invZ[tid] = iz;
        entP[tid] = ez * iz;
    }
    __syncthreads();

    // sweep 3: normalized probs -> LDS (pad cols select 0)
    float izl[4];
    #pragma unroll
    for (int j = 0; j < 4; ++j) izl[j] = invZ[g * 4 + j];
    #pragma unroll
    for (int tt = 0; tt < 13; ++tt) {
        int gt = w * 13 + tt;
        int col = gt * 16 + lr;
        #pragma unroll
        for (int j = 0; j < 4; ++j) {
            float v = acc[tt][j] * izl[j];
            if (gt >= 49) v = 0.f;
            otile[g * 4 + j][col] = f2bf(v);
        }
    }
    __syncthreads();
    if (tid < 16) otile[tid][784] = f2bf(entP[tid]);
    __syncthreads();

    for (int v = tid; v < 16 * 104; v += 256) {
        int row = v / 104, cv = v % 104;
        *(u16x8*)(OUT + (size_t)(r0 + row) * Pp + cv * 8) = *(const u16x8*)(&otile[row][cv * 8]);
    }
}

// ---------------- K2: dual-output affinity — shared B-panel (halved L2 traffic) ----------------
// grid 1568 = 8 XCDs * (4 groups * 49 strips). Group k<6: pair {side0 t=k, side1 t=5-k}
// sharing B=q[k+1]; k==6: single side0 t=6 (B=q[7]); k==7: single side1 t=6 (B=q[0]).
__global__ __launch_bounds__(256) void k_affinity(const unsigned short* __restrict__ qTb,
                                                  unsigned short* __restrict__ P12h,
                                                  unsigned short* __restrict__ P21h,
                                                  float* __restrict__ cs12,
                                                  float* __restrict__ cs21,
                                                  float wconst)
{
    const size_t MMp = (size_t)Pp * Pp;
    __shared__ unsigned short otile[16][840];
    __shared__ float sred[16][4][2];
    __shared__ float rowsum[16], invZ[16], entP[16];

    int f = blockIdx.x;
    int xcd = f & 7, slot = f >> 3;
    int grp = xcd + 8 * (slot / 49);       // 0..31
    int strip = slot % 49;
    int b = grp >> 3, k = grp & 7;
    bool pairb = (k < 6);

    // B panel (shared): q[k+1] for k<6; q[7] for k==6; q[0] for k==7.
    int tB = (k < 6) ? (k + 1) : ((k == 6) ? 7 : 0);
    const unsigned short* Bq = qTb + (size_t)(b * Tc + tB) * Qrows * Dc;

    // output 0: k<=6 -> side0 t=k (A=q[k], OUT=P12h[b7+k], cs=cs21[b7+6-k])
    //           k==7 -> side1 t=6 (A=q[1], OUT=P21h[b7+6], cs=cs12[b7+0])
    const unsigned short* Aq0;
    unsigned short* OUT0;
    float* cs0;
    if (k <= 6) {
        Aq0 = qTb + (size_t)(b * Tc + k) * Qrows * Dc;
        OUT0 = P12h + (size_t)(b * TM1 + k) * MMp;
        cs0  = cs21 + (size_t)(b * TM1 + (6 - k)) * Pp;
    } else {
        Aq0 = qTb + (size_t)(b * Tc + 1) * Qrows * Dc;
        OUT0 = P21h + (size_t)(b * TM1 + 6) * MMp;
        cs0  = cs12 + (size_t)(b * TM1 + 0) * Pp;
    }
    // output 1 (pairs only): side1 t=5-k (A=q[k+2], OUT=P21h[b7+5-k], cs=cs12[b7+k+1])
    const unsigned short* Aq1 = qTb + (size_t)(b * Tc + k + 2) * Qrows * Dc;
    unsigned short* OUT1 = P21h + (size_t)(b * TM1 + (5 - k)) * MMp;
    float* cs1 = cs12 + (size_t)(b * TM1 + (k + 1)) * Pp;

    const int r0 = strip * 16;
    const int tid = threadIdx.x, lane = tid & 63, w = tid >> 6;
    const int g = lane >> 4, lr = lane & 15;

    f32x4 acc0[13] = {}, acc1[13] = {};
    #pragma unroll
    for (int ks = 0; ks < 4; ++ks) {
        bf16x8 af0 = __builtin_bit_cast(bf16x8,
            *(const u16x8*)(Aq0 + (size_t)(r0 + lr) * Dc + ks * 32 + g * 8));
        bf16x8 bfr[13];
        #pragma unroll
        for (int tt = 0; tt < 13; ++tt)
            bfr[tt] = __builtin_bit_cast(bf16x8,
                *(const u16x8*)(Bq + (size_t)((w * 13 + tt) * 16 + lr) * Dc + ks * 32 + g * 8));
        #pragma unroll
        for (int tt = 0; tt < 13; ++tt)
            acc0[tt] = __builtin_amdgcn_mfma_f32_16x16x32_bf16(af0, bfr[tt], acc0[tt], 0, 0, 0);
        if (pairb) {
            bf16x8 af1 = __builtin_bit_cast(bf16x8,
                *(const u16x8*)(Aq1 + (size_t)(r0 + lr) * Dc + ks * 32 + g * 8));
            #pragma unroll
            for (int tt = 0; tt < 13; ++tt)
                acc1[tt] = __builtin_amdgcn_mfma_f32_16x16x32_bf16(af1, bfr[tt], acc1[tt], 0, 0, 0);
        }
    }

    aff_process(acc0, OUT0, cs0, r0, tid, w, g, lr, wconst, otile, sred, rowsum, invZ, entP);
    if (pairb)
        aff_process(acc1, OUT1, cs1, r0, tid, w, g, lr, wconst, otile, sred, rowsum, invZ, entP);
}

// ---------------- K3: dust rows (row 784) + zero pad rows ----------------
__global__ __launch_bounds__(256) void k_dustrow(const float* __restrict__ cs12,
                                                 const float* __restrict__ cs21,
                                                 unsigned short* __restrict__ P12h,
                                                 unsigned short* __restrict__ P21h)
{
    constexpr float INVT = 1.0f / TEMP;
    const size_t MMp = (size_t)Pp * Pp;
    int bt = blockIdx.x, side = blockIdx.y;
    const float* cs = (side ? cs21 : cs12) + (size_t)bt * Pp;
    unsigned short* OUT = (side ? P21h : P12h) + (size_t)bt * MMp;
    __shared__ float sbuf[4];
    int tid = threadIdx.x;
    float v[4];
    #pragma unroll
    for (int k = 0; k < 4; ++k) {
        int j = tid + k * 256;
        float val = -INFINITY;
        if (j < Nc)       val = -cs[j] * INVT;
        else if (j == Nc) val = 0.f;
        v[k] = val;
    }
    float mx = fmaxf(fmaxf(v[0], v[1]), fmaxf(v[2], v[3]));
    mx = blockReduceMax(mx, sbuf);
    float e[4]; float s = 0.f;
    #pragma unroll
    for (int k = 0; k < 4; ++k) {
        int j = tid + k * 256;
        e[k] = (j < Mc) ? __expf(v[k] - mx) : 0.f;
        s += e[k];
    }
    s = blockReduceSum(s, sbuf);
    float invs = 1.f / s;
    #pragma unroll
    for (int k = 0; k < 4; ++k) {
        int j = tid + k * 256;
        if (j < Mc)      OUT[(size_t)Nc * Pp + j] = f2bf(e[k] * invs);
        else if (j < Pp) OUT[(size_t)Nc * Pp + j] = 0;
    }
    u16x8 z = {};
    u16x8* dst = (u16x8*)(OUT + (size_t)785 * Pp);
    for (int i = tid; i < (Pp - 785) * Pp / 8; i += 256) dst[i] = z;
}

// ---------------- K6: merged bf16 transposes (grid z = 0..27) ----------------
__global__ __launch_bounds__(256) void k_transpose_bf16(const unsigned short* __restrict__ P12h,
                                                        const unsigned short* __restrict__ P21h,
                                                        unsigned short* __restrict__ Db)
{
    const size_t MMp = (size_t)Pp * Pp;
    __shared__ unsigned short tile[64][65];
    int z = blockIdx.z;
    const unsigned short* S;
    if (z < 24) { int b = z / 6, tm = z % 6; S = P12h + ((size_t)b * 7 + tm + 1) * MMp; }
    else        { S = P21h + ((size_t)(z - 24) * 7 + 6) * MMp; }
    unsigned short* D = Db + (size_t)z * MMp;
    int x0 = blockIdx.x * 64, y0 = blockIdx.y * 64;
    int tx = threadIdx.x & 63, ty = threadIdx.x >> 6;
    #pragma unroll
    for (int y = 0; y < 64; y += 4) tile[y + ty][tx] = S[(size_t)(y0 + y + ty) * Pp + x0 + tx];
    __syncthreads();
    #pragma unroll
    for (int y = 0; y < 64; y += 4) D[(size_t)(x0 + y + ty) * Pp + y0 + tx] = tile[tx][y + ty];
}

// ---------------- K7: fused chain GEMM (64x128 db tiles) + loss ----------------
struct GJobs {
    const unsigned short* A[2];
    const unsigned short* BT[2];
    unsigned short* Cb[2];
    float* cs[2];
    long long sA[2], sB[2], sC[2];
    const unsigned short* Lr;
    const unsigned short* Rr;
    const float* csL;
    float* loss;
    float scale;
};

__global__ __launch_bounds__(256, 3) void k_gemm_loss(GJobs J)
{
    const size_t MMp = (size_t)Pp * Pp;
    if (blockIdx.x >= 728) {
        int q = blockIdx.x - 728;
        int w = threadIdx.x >> 6, lane = threadIdx.x & 63;
        int r = q * 4 + w;
        int b = r / Mc, i = r % Mc;
        const u16x8* lrow = (const u16x8*)(J.Lr + (size_t)b * MMp + (size_t)i * Pp);
        const u16x8* rrow = (const u16x8*)(J.Rr + (size_t)b * MMp + (size_t)i * Pp);
        const f32x4* cs4  = (const f32x4*)(J.csL + (size_t)b * Pp);
        float sR = 0.f, sD = 0.f;
        for (int c = lane; c < Pp / 8; c += 64) {
            u16x8 lv = lrow[c];
            u16x8 rv = rrow[c];
            f32x4 c0 = cs4[2 * c], c1 = cs4[2 * c + 1];
            #pragma unroll
            for (int k = 0; k < 4; ++k) {
                float fl = bf2f(lv[k]);
                sR += fl * c0[k];
                sD += fl * bf2f(rv[k]);
            }
            #pragma unroll
            for (int k = 0; k < 4; ++k) {
                float fl = bf2f(lv[4 + k]);
                sR += fl * c1[k];
                sD += fl * bf2f(rv[4 + k]);
            }
        }
        #pragma unroll
        for (int off = 1; off <= 32; off <<= 1) {
            sR += __shfl_xor(sR, off, 64);
            sD += __shfl_xor(sD, off, 64);
        }
        if (lane == 0)
            atomicAdd(J.loss, (logf(sR + Mc * 1e-20f) - logf(sD + 1e-20f)) * J.scale);
        return;
    }

    __shared__ __align__(16) unsigned short As0[64 * 64], As1[64 * 64];
    __shared__ __align__(16) unsigned short Bs0[128 * 64], Bs1[128 * 64];

    int f = blockIdx.x;
    int zz = f & 7, slot = f >> 3;
    int job = zz >> 2, b = zz & 3;
    const unsigned short* A  = J.A[job]  + (size_t)b * J.sA[job];
    const unsigned short* BT = J.BT[job] + (size_t)b * J.sB[job];

    const int i0 = (slot / 7) * 64, j0 = (slot % 7) * 128;
    const int tid = threadIdx.x, lane = tid & 63, wv = tid >> 6;
    const int g = lane >> 4, lr = lane & 15;

    f32x4 acc[4][2] = {};
    gemm64x128_db<Pp>(A, BT, As0, As1, Bs0, Bs1, i0, j0, tid, acc);

    unsigned short* Co = J.Cb[job] + (size_t)b * J.sC[job];
    float* csp = J.cs[job];
    float csacc[2] = {0.f, 0.f};
    #pragma unroll
    for (int m = 0; m < 4; ++m)
        #pragma unroll
        for (int n = 0; n < 2; ++n)
            #pragma unroll
            for (int j = 0; j < 4; ++j) {
                int row = i0 + m * 16 + g * 4 + j;
                int col = j0 + wv * 32 + n * 16 + lr;
                if (col < Pp) {
                    unsigned short h = f2bf(acc[m][n][j]);
                    Co[(size_t)row * Pp + col] = h;
                    csacc[n] += bf2f(h);
                }
            }
    if (csp) {
        csp += (size_t)b * Pp;
        #pragma unroll
        for (int n = 0; n < 2; ++n) {
            float p = csacc[n];
            p += __shfl_xor(p, 16, 64);
            p += __shfl_xor(p, 32, 64);
            int col = j0 + wv * 32 + n * 16 + lr;
            if (g == 0 && col < Pp) atomicAdd(&csp[col], p);
        }
    }
}

// ---------------- K8: standalone loss rows (final step) ----------------
__global__ __launch_bounds__(64) void k_lossrow(const unsigned short* __restrict__ L,
                                                const unsigned short* __restrict__ R,
                                                const float* __restrict__ csR,
                                                float* __restrict__ loss, float scale)
{
    const size_t MMp = (size_t)Pp * Pp;
    int r = blockIdx.x;
    int b = r / Mc, i = r % Mc;
    const u16x8* lrow = (const u16x8*)(L + (size_t)b * MMp + (size_t)i * Pp);
    const u16x8* rrow = (const u16x8*)(R + (size_t)b * MMp + (size_t)i * Pp);
    const f32x4* cs4  = (const f32x4*)(csR + (size_t)b * Pp);
    int lane = threadIdx.x;
    float sR = 0.f, sD = 0.f;
    for (int c = lane; c < Pp / 8; c += 64) {
        u16x8 lv = lrow[c];
        u16x8 rv = rrow[c];
        f32x4 c0 = cs4[2 * c], c1 = cs4[2 * c + 1];
        #pragma unroll
        for (int k = 0; k < 4; ++k) {
            float fl = bf2f(lv[k]);
            sR += fl * c0[k];
            sD += fl * bf2f(rv[k]);
        }
        #pragma unroll
        for (int k = 0; k < 4; ++k) {
            float fl = bf2f(lv[4 + k]);
            sR += fl * c1[k];
            sD += fl * bf2f(rv[4 + k]);
        }
    }
    #pragma unroll
    for (int off = 1; off <= 32; off <<= 1) {
        sR += __shfl_xor(sR, off, 64);
        sD += __shfl_xor(sD, off, 64);
    }
    if (lane == 0)
        atomicAdd(loss, (logf(sR + Mc * 1e-20f) - logf(sD + 1e-20f)) * scale);
}

// ---------------- host orchestration ----------------
extern "C" void kernel_launch(void* const* d_in, const int* in_sizes, int n_in,
                              void* d_out, int out_size, void* d_ws, size_t ws_size,
                              hipStream_t stream)
{
    const float* feats = (const float*)d_in[0];
    const float* dust  = (const float*)d_in[1];
    const float* Wself = (const float*)d_in[2];
    const float* bself = (const float*)d_in[3];
    const float* Wdust = (const float*)d_in[4];
    const float* bdust = (const float*)d_in[5];

    float* out  = (float*)d_out;
    float* qout = out;
    float* loss = out + (size_t)Bc * Dc * Tc * Mc;

    const size_t MMp = (size_t)Pp * Pp;       // 692,224

    // ---- workspace ----
    float* ws = (float*)d_ws;
    float* csR = ws;                                                // 6 slots * Bc * Pp fp32
    unsigned short* P12h = (unsigned short*)(ws + 4 * MMp);         // 28*MMp bf16
    unsigned short* P21h = P12h + (size_t)28 * MMp;                 // 28*MMp bf16
    unsigned short* chainT = P21h + (size_t)28 * MMp;               // 44*MMp bf16 region
    unsigned short* P12T  = chainT;
    unsigned short* P21T6 = P12T + (size_t)24 * MMp;
    unsigned short* l0    = P21T6 + (size_t)4 * MMp;
    unsigned short* l1    = l0 + (size_t)4 * MMp;
    unsigned short* R0    = l1 + (size_t)4 * MMp;
    unsigned short* R1    = R0 + (size_t)4 * MMp;
    unsigned short* qTb   = R1 + (size_t)4 * MMp;                   // 32*Qrows*Dc bf16
    float* cs12 = (float*)(qTb + (size_t)32 * Qrows * Dc);          // 28*Pp fp32
    float* cs21 = cs12 + (size_t)28 * Pp;                           // 28*Pp fp32

    // phase-1 overlays in chainT region:
    unsigned short* Abf   = chainT;
    unsigned int*   Abf32 = (unsigned int*)Abf;
    unsigned short* WTb   = Abf + (size_t)Bc * Tc * Nc * Cc;
    float*          fbuf  = (float*)(WTb + 2 * (size_t)Dc * Cc);

    // 1. pack inputs (+W pack +zero roles incl. qTb pad rows)
    k_pack<<<Bc * Nc + 32 + 8, 256, 0, stream>>>(feats, Wself, Wdust, Abf32, WTb, qTb, csR, loss);
    // 2. projection GEMM + bias (64x128 tiles)
    k_gemm_proj<<<392, 256, 0, stream>>>(Abf, WTb, bself, fbuf);
    // 3. norms (+dust projection role; qTb row 784 stays zero)
    k_norm<<<dim3(14, 32), 256, 0, stream>>>(fbuf, dust, Wdust, bdust, qTb, qout);
    // 4. dual-output affinity (shared B-panels), then dust rows
    float wconst = (float)(1.0 / log(784.0));
    k_affinity<<<1568, 256, 0, stream>>>(qTb, P12h, P21h, cs12, cs21, wconst);
    k_dustrow<<<dim3(28, 2), 256, 0, stream>>>(cs12, cs21, P12h, P21h);
    // 5. merged bf16 transposes
    k_transpose_bf16<<<dim3(13, 13, 28), 256, 0, stream>>>(P12h, P21h, P12T);

    // 6. chain
    const float scale = 1.0f / (6.0f * Bc * Mc);

    {
        GJobs J = {};
        J.A[0] = P12h;  J.sA[0] = (long long)7 * MMp;
        J.BT[0] = P12T; J.sB[0] = (long long)6 * MMp;
        J.Cb[0] = l0;   J.sC[0] = (long long)MMp; J.cs[0] = nullptr;
        J.A[1] = P21T6;                   J.sA[1] = (long long)MMp;
        J.BT[1] = P21h + (size_t)5 * MMp; J.sB[1] = (long long)7 * MMp;
        J.Cb[1] = R0;   J.sC[1] = (long long)MMp; J.cs[1] = csR;   // slot 0
        k_gemm_loss<<<728, 256, 0, stream>>>(J);
    }

    unsigned short *lcur = l0, *lnxt = l1, *rcur = R0, *rnxt = R1;
    for (int i = 1; i <= 5; ++i) {
        GJobs J = {};
        J.A[0] = lcur; J.sA[0] = (long long)MMp;
        J.BT[0] = P12T + (size_t)i * MMp; J.sB[0] = (long long)6 * MMp;
        J.Cb[0] = lnxt; J.sC[0] = (long long)MMp; J.cs[0] = nullptr;
        J.A[1] = rcur; J.sA[1] = (long long)MMp;
        J.BT[1] = P21h + (size_t)(5 - i) * MMp; J.sB[1] = (long long)7 * MMp;
        J.Cb[1] = rnxt; J.sC[1] = (long long)MMp; J.cs[1] = csR + (size_t)i * Bc * Pp;
        J.Lr = lcur; J.Rr = rcur; J.csL = csR + (size_t)(i - 1) * Bc * Pp;
        J.loss = loss; J.scale = scale;
        k_gemm_loss<<<728 + 785, 256, 0, stream>>>(J);
        unsigned short* t;
        t = lcur; lcur = lnxt; lnxt = t;
        t = rcur; rcur = rnxt; rnxt = t;
    }
    // final loss (state 6)
    k_lossrow<<<Bc * Mc, 64, 0, stream>>>(lcur, rcur, csR + (size_t)5 * Bc * Pp, loss, scale);
}

// Round 16
// 435.169 us; speedup vs baseline: 1.0977x; 1.0977x over previous
//
#include <hip/hip_runtime.h>
#include <hip/hip_bf16.h>
#include <math.h>

// Problem constants
constexpr int Bc = 4;      // batch
constexpr int Nc = 784;    // tokens
constexpr int Cc = 512;    // enc channels
constexpr int Tc = 8;      // time
constexpr int Dc = 128;    // proj dim
constexpr int Mc = 785;    // N+1
constexpr int TM1 = 7;     // T-1
constexpr int Pp = 832;    // padded chain dim (13*64)
constexpr int Qrows = 896; // padded q rows
constexpr float TEMP = 0.07f;

typedef __attribute__((ext_vector_type(4))) float f32x4;
typedef __attribute__((ext_vector_type(8))) unsigned short u16x8;
typedef __attribute__((ext_vector_type(8))) __bf16 bf16x8;

__device__ __forceinline__ unsigned short f2bf(float v) {
    __hip_bfloat16 h = __float2bfloat16(v);
    return __builtin_bit_cast(unsigned short, h);
}
__device__ __forceinline__ float bf2f(unsigned short u) {
    return __builtin_bit_cast(float, (unsigned int)u << 16);
}

// ---------------- async 16B global->LDS ----------------
__device__ __forceinline__ void gload16(const void* g, void* l) {
    __builtin_amdgcn_global_load_lds(
        (const __attribute__((address_space(1))) unsigned int*)g,
        (__attribute__((address_space(3))) unsigned int*)l, 16, 0, 0);
}

// ---------------- shared 64x128 double-buffered MFMA K-loop ----------------
template<int LD>
__device__ __forceinline__ void gemm64x128_db(const unsigned short* __restrict__ A,
                                              const unsigned short* __restrict__ BT,
                                              unsigned short* As0, unsigned short* As1,
                                              unsigned short* Bs0, unsigned short* Bs1,
                                              int i0, int j0, int tid, f32x4 (&acc)[4][2])
{
    const int lane = tid & 63, wv = tid >> 6;
    const int g = lane >> 4, lr = lane & 15;
    constexpr int NT = LD / 64;

    #pragma unroll
    for (int q = 0; q < 2; ++q) {
        int s = q * 256 + tid; int r = s >> 3;
        int csw = ((s & 7) << 4) ^ ((r & 7) << 4);
        gload16((const char*)(A + (size_t)(i0 + r) * LD) + csw, As0 + (size_t)s * 8);
    }
    #pragma unroll
    for (int q = 0; q < 4; ++q) {
        int s = q * 256 + tid; int r = s >> 3;
        int csw = ((s & 7) << 4) ^ ((r & 7) << 4);
        gload16((const char*)(BT + (size_t)(j0 + r) * LD) + csw, Bs0 + (size_t)s * 8);
    }
    __syncthreads();

    for (int t = 0; t < NT; ++t) {
        unsigned short* Asc = (t & 1) ? As1 : As0;
        unsigned short* Bsc = (t & 1) ? Bs1 : Bs0;
        if (t + 1 < NT) {
            int k0 = (t + 1) * 64;
            unsigned short* Asn = (t & 1) ? As0 : As1;
            unsigned short* Bsn = (t & 1) ? Bs0 : Bs1;
            #pragma unroll
            for (int q = 0; q < 2; ++q) {
                int s = q * 256 + tid; int r = s >> 3;
                int csw = ((s & 7) << 4) ^ ((r & 7) << 4);
                gload16((const char*)(A + (size_t)(i0 + r) * LD + k0) + csw, Asn + (size_t)s * 8);
            }
            #pragma unroll
            for (int q = 0; q < 4; ++q) {
                int s = q * 256 + tid; int r = s >> 3;
                int csw = ((s & 7) << 4) ^ ((r & 7) << 4);
                gload16((const char*)(BT + (size_t)(j0 + r) * LD + k0) + csw, Bsn + (size_t)s * 8);
            }
        }
        bf16x8 af[2][4], bf[2][2];
        #pragma unroll
        for (int ks = 0; ks < 2; ++ks) {
            #pragma unroll
            for (int m = 0; m < 4; ++m) {
                int r = m * 16 + lr;
                int cb = (ks * 64 + g * 16) ^ ((r & 7) << 4);
                af[ks][m] = __builtin_bit_cast(bf16x8, *(const u16x8*)((const char*)Asc + r * 128 + cb));
            }
            #pragma unroll
            for (int n = 0; n < 2; ++n) {
                int r = wv * 32 + n * 16 + lr;
                int cb = (ks * 64 + g * 16) ^ ((r & 7) << 4);
                bf[ks][n] = __builtin_bit_cast(bf16x8, *(const u16x8*)((const char*)Bsc + r * 128 + cb));
            }
        }
        #pragma unroll
        for (int ks = 0; ks < 2; ++ks)
            #pragma unroll
            for (int m = 0; m < 4; ++m)
                #pragma unroll
                for (int n = 0; n < 2; ++n)
                    acc[m][n] = __builtin_amdgcn_mfma_f32_16x16x32_bf16(af[ks][m], bf[ks][n], acc[m][n], 0, 0, 0);
        __syncthreads();
    }
}

// ---------------- reduction helpers ----------------
__device__ __forceinline__ float blockReduceSum(float v, float* sbuf) {
    #pragma unroll
    for (int off = 32; off; off >>= 1) v += __shfl_down(v, off, 64);
    __syncthreads();
    if ((threadIdx.x & 63) == 0) sbuf[threadIdx.x >> 6] = v;
    __syncthreads();
    return sbuf[0] + sbuf[1] + sbuf[2] + sbuf[3];
}
__device__ __forceinline__ float blockReduceMax(float v, float* sbuf) {
    #pragma unroll
    for (int off = 32; off; off >>= 1) v = fmaxf(v, __shfl_down(v, off, 64));
    __syncthreads();
    if ((threadIdx.x & 63) == 0) sbuf[threadIdx.x >> 6] = v;
    __syncthreads();
    return fmaxf(fmaxf(sbuf[0], sbuf[1]), fmaxf(sbuf[2], sbuf[3]));
}

// ---------------- K1a: pack feats + pack W + zero-init roles ----------------
// bid < 3136: feats pack; [3136,3168): W pack; [3168,3176): zero roles
// (csR+loss on first; qTb pad rows 784..895 split across all 8).
__global__ __launch_bounds__(256) void k_pack(const float* __restrict__ feats,
                                              const float* __restrict__ Wself,
                                              const float* __restrict__ Wdust,
                                              unsigned int* __restrict__ Abf32,
                                              unsigned short* __restrict__ WTb,
                                              unsigned short* __restrict__ qTb,
                                              float* __restrict__ csR,
                                              float* __restrict__ loss)
{
    __shared__ float lds[Cc * 9];
    int bid = blockIdx.x;
    int tid = threadIdx.x;
    if (bid >= Bc * Nc + 32) {
        // zero role
        int zb = bid - (Bc * Nc + 32);     // 0..7
        if (zb == 0) {
            int n = 6 * Bc * Pp;
            for (int i = tid; i < n; i += 256) csR[i] = 0.f;
            if (tid == 0) *loss = 0.f;
        }
        u16x8 z = {};
        for (int bt = zb * 4; bt < zb * 4 + 4; ++bt) {
            u16x8* dst = (u16x8*)(qTb + ((size_t)bt * Qrows + Nc) * Dc);
            for (int i = tid; i < (Qrows - Nc) * Dc / 8; i += 256) dst[i] = z;
        }
        return;
    }
    if (bid >= Bc * Nc) {
        // packw role
        int pidx = bid - Bc * Nc;
        int which = pidx >> 4;
        int rem = pidx & 15;
        int d0 = (rem >> 3) * 64, c0 = (rem & 7) * 64;
        const float* W = which ? Wdust : Wself;
        unsigned short* O = WTb + (size_t)which * Dc * Cc;
        int tx = tid & 63, ty = tid >> 6;
        #pragma unroll
        for (int y = 0; y < 64; y += 4) lds[(y + ty) * 65 + tx] = W[(size_t)(c0 + y + ty) * Dc + d0 + tx];
        __syncthreads();
        #pragma unroll
        for (int y = 0; y < 64; y += 4) O[(size_t)(d0 + y + ty) * Cc + c0 + tx] = f2bf(lds[tx * 65 + y + ty]);
        return;
    }
    // feats pack role
    int b = bid / Nc, n = bid % Nc;
    const float* src = feats + (size_t)(b * Nc + n) * Cc * Tc;
    for (int i = tid; i < Cc * Tc; i += 256) lds[(i >> 3) * 9 + (i & 7)] = src[i];
    __syncthreads();
    #pragma unroll
    for (int t = 0; t < Tc; ++t) {
        size_t row = (size_t)(b * Tc + t) * Nc + n;
        float v0 = lds[(2 * tid) * 9 + t];
        float v1 = lds[(2 * tid + 1) * 9 + t];
        unsigned int pk = (unsigned int)f2bf(v0) | ((unsigned int)f2bf(v1) << 16);
        Abf32[row * (Cc / 2) + tid] = pk;
    }
}

// ---------------- K1c: projection GEMM fbuf = Abf @ WT^T + bias ----------------
__global__ __launch_bounds__(256, 3) void k_gemm_proj(const unsigned short* __restrict__ A,
                                                      const unsigned short* __restrict__ BT,
                                                      const float* __restrict__ bias,
                                                      float* __restrict__ Cf)
{
    __shared__ __align__(16) unsigned short As0[64 * 64], As1[64 * 64];
    __shared__ __align__(16) unsigned short Bs0[128 * 64], Bs1[128 * 64];
    const int i0 = blockIdx.x * 64;
    const int tid = threadIdx.x, lane = tid & 63, wv = tid >> 6;
    const int g = lane >> 4, lr = lane & 15;

    f32x4 acc[4][2] = {};
    gemm64x128_db<Cc>(A, BT, As0, As1, Bs0, Bs1, i0, 0, tid, acc);

    #pragma unroll
    for (int n = 0; n < 2; ++n) {
        int col = wv * 32 + n * 16 + lr;
        float bv = bias[col];
        #pragma unroll
        for (int m = 0; m < 4; ++m)
            #pragma unroll
            for (int j = 0; j < 4; ++j) {
                int row = i0 + m * 16 + g * 4 + j;
                Cf[(size_t)row * Dc + col] = acc[m][n][j] + bv;
            }
    }
}

// ---------------- K1e: l2norm rows -> bf16 qTb + fp32 qout (+dust role) ----------------
// Dust role writes qout ONLY (qTb row 784 must stay ZERO for the padded affinity).
__global__ __launch_bounds__(256) void k_norm(const float* __restrict__ fbuf,
                                              const float* __restrict__ dust,
                                              const float* __restrict__ Wdust,
                                              const float* __restrict__ bdust,
                                              unsigned short* __restrict__ qTb,
                                              float* __restrict__ qout)
{
    __shared__ float lds[64][129];
    __shared__ float nrm[64][4];
    __shared__ float inv[64];
    __shared__ float red2[2];
    int bt = blockIdx.y;
    int b = bt >> 3, t = bt & 7;
    int tid = threadIdx.x;

    if (blockIdx.x == 13) {
        float* sdust = &lds[0][0];
        for (int i = tid; i < Cc; i += 256) sdust[i] = dust[((size_t)b * Cc + i) * Tc + t];
        __syncthreads();
        float acc = 0.f;
        if (tid < 128) {
            for (int c = 0; c < Cc; ++c) acc += sdust[c] * Wdust[(size_t)c * Dc + tid];
            acc += bdust[tid];
            float s = acc * acc;
            #pragma unroll
            for (int off = 32; off; off >>= 1) s += __shfl_down(s, off, 64);
            if ((tid & 63) == 0) red2[tid >> 6] = s;
        }
        __syncthreads();
        if (tid < 128) {
            float inv0 = 1.f / fmaxf(sqrtf(red2[0] + red2[1]), 1e-12f);
            float qv = acc * inv0;
            qout[(((size_t)b * Dc + tid) * Tc + t) * Mc + Nc] = qv;
        }
        return;
    }

    int n0 = blockIdx.x * 64;
    #pragma unroll
    for (int q = 0; q < 8; ++q) {
        int i = q * 256 + tid;
        int nl = i >> 5, d4 = i & 31;
        f32x4 v = {};
        if (n0 + nl < Nc) v = *(const f32x4*)(fbuf + ((size_t)bt * Nc + n0 + nl) * Dc + d4 * 4);
        *(f32x4*)(&lds[nl][d4 * 4]) = v;
    }
    __syncthreads();
    {
        int r = tid & 63, p = tid >> 6;
        float s = 0.f;
        #pragma unroll
        for (int j = 0; j < 32; ++j) { float v = lds[r][p * 32 + j]; s += v * v; }
        nrm[r][p] = s;
    }
    __syncthreads();
    if (tid < 64) inv[tid] = 1.f / fmaxf(sqrtf(nrm[tid][0] + nrm[tid][1] + nrm[tid][2] + nrm[tid][3]), 1e-12f);
    __syncthreads();
    unsigned int* qT32 = (unsigned int*)(qTb + (size_t)bt * Qrows * Dc);
    #pragma unroll
    for (int q = 0; q < 16; ++q) {
        int i = q * 256 + tid;
        int nl = i >> 6, dp = i & 63;
        if (n0 + nl < Nc) {
            float iv = inv[nl];
            unsigned int pk = (unsigned int)f2bf(lds[nl][2 * dp] * iv)
                            | ((unsigned int)f2bf(lds[nl][2 * dp + 1] * iv) << 16);
            qT32[((size_t)(n0 + nl) * Dc >> 1) + dp] = pk;
        }
    }
    int nl = tid & 63;
    if (n0 + nl < Nc) {
        float iv = inv[nl];
        #pragma unroll
        for (int dd = 0; dd < Dc; dd += 4) {
            int d = dd + (tid >> 6);
            qout[(((size_t)b * Dc + d) * Tc + t) * Mc + n0 + nl] = lds[nl][d] * iv;
        }
    }
}

// ---------------- K2: fused affinity — GUARD-FREE hot path (round-14 best) ----------------
// Tiles padded to 52 (rows 784..831 of qTb are ZERO): pad tiles give acc==0
// exactly, so rowsum/colsum/entropy need no guards; esum corrected by the
// exact exp(0)=1 count (wave 3 has 3 pad tiles); sweep-3 selects 0 for pad.
__global__ __launch_bounds__(256, 2) void k_affinity(const unsigned short* __restrict__ qTb,
                                                     unsigned short* __restrict__ P12h,
                                                     unsigned short* __restrict__ P21h,
                                                     float* __restrict__ cs12,
                                                     float* __restrict__ cs21,
                                                     float wconst)
{
    constexpr float INVT = 1.0f / TEMP;
    const size_t MMp = (size_t)Pp * Pp;
    __shared__ unsigned short otile[16][840];
    __shared__ float sred[16][4][2];
    __shared__ float rowsum[16], invZ[16], entP[16];

    int f = blockIdx.x;
    int xcd = f & 7, slot = f >> 3;
    int grp = xcd + 8 * (slot / 49);
    int strip = slot % 49;
    int side = grp >= 28 ? 1 : 0;
    int bt = grp - side * 28;
    int b = bt / TM1, t = bt % TM1;
    const unsigned short *Aq, *Bq;
    unsigned short* OUT;
    if (side == 0) {
        Aq = qTb + (size_t)(b * Tc + t)     * Qrows * Dc;
        Bq = qTb + (size_t)(b * Tc + t + 1) * Qrows * Dc;
        OUT = P12h + (size_t)bt * MMp;
    } else {
        Aq = qTb + (size_t)(b * Tc + 7 - t) * Qrows * Dc;
        Bq = qTb + (size_t)(b * Tc + 6 - t) * Qrows * Dc;
        OUT = P21h + (size_t)bt * MMp;
    }
    float* csFlip = (side == 0 ? cs21 : cs12) + (size_t)(b * TM1 + (6 - t)) * Pp;

    const int r0 = strip * 16;
    const int tid = threadIdx.x, lane = tid & 63, w = tid >> 6;
    const int g = lane >> 4, lr = lane & 15;

    // straight-line MFMA: 13 tiles per wave, no guards (pad tiles hit zero rows)
    f32x4 acc[13] = {};
    #pragma unroll
    for (int ks = 0; ks < 4; ++ks) {
        bf16x8 af = __builtin_bit_cast(bf16x8,
            *(const u16x8*)(Aq + (size_t)(r0 + lr) * Dc + ks * 32 + g * 8));
        bf16x8 bfr[13];
        #pragma unroll
        for (int tt = 0; tt < 13; ++tt)
            bfr[tt] = __builtin_bit_cast(bf16x8,
                *(const u16x8*)(Bq + (size_t)((w * 13 + tt) * 16 + lr) * Dc + ks * 32 + g * 8));
        #pragma unroll
        for (int tt = 0; tt < 13; ++tt)
            acc[tt] = __builtin_amdgcn_mfma_f32_16x16x32_bf16(af, bfr[tt], acc[tt], 0, 0, 0);
    }

    // sweep 1: rowsums (pad tiles contribute exactly 0)
    float rs[4] = {0.f, 0.f, 0.f, 0.f};
    #pragma unroll
    for (int tt = 0; tt < 13; ++tt) {
        #pragma unroll
        for (int j = 0; j < 4; ++j) rs[j] += acc[tt][j];
    }
    #pragma unroll
    for (int off = 1; off <= 8; off <<= 1) {
        #pragma unroll
        for (int j = 0; j < 4; ++j) rs[j] += __shfl_xor(rs[j], off, 64);
    }
    if (lr == 0) {
        #pragma unroll
        for (int j = 0; j < 4; ++j) sred[g * 4 + j][w][0] = rs[j];
    }
    __syncthreads();
    if (tid < 16) {
        float r = sred[tid][0][0] + sred[tid][1][0] + sred[tid][2][0] + sred[tid][3][0];
        rowsum[tid] = r;
        csFlip[r0 + tid] = r;
    }
    __syncthreads();

    // sweep 2: exp-sum + entropy (pad: exp(0)=1 -> exact scalar correction; en adds 0)
    float invr[4];
    #pragma unroll
    for (int j = 0; j < 4; ++j) invr[j] = 1.0f / rowsum[g * 4 + j];
    const float padc = (w == 3) ? 3.0f : 0.0f;
    float en[4] = {0.f, 0.f, 0.f, 0.f}, es[4] = {0.f, 0.f, 0.f, 0.f};
    #pragma unroll
    for (int tt = 0; tt < 13; ++tt) {
        #pragma unroll
        for (int j = 0; j < 4; ++j) {
            float a = acc[tt][j];
            float e = __expf(a * INVT);
            es[j] += e;
            float p = a * invr[j];
            en[j] -= p * __logf(fmaxf(p, 1e-20f));
            acc[tt][j] = e;
        }
    }
    #pragma unroll
    for (int j = 0; j < 4; ++j) es[j] -= padc;
    #pragma unroll
    for (int off = 1; off <= 8; off <<= 1) {
        #pragma unroll
        for (int j = 0; j < 4; ++j) {
            es[j] += __shfl_xor(es[j], off, 64);
            en[j] += __shfl_xor(en[j], off, 64);
        }
    }
    if (lr == 0) {
        #pragma unroll
        for (int j = 0; j < 4; ++j) { sred[g * 4 + j][w][0] = es[j]; sred[g * 4 + j][w][1] = en[j]; }
    }
    __syncthreads();
    if (tid < 16) {
        float esum = sred[tid][0][0] + sred[tid][1][0] + sred[tid][2][0] + sred[tid][3][0];
        float ent  = sred[tid][0][1] + sred[tid][1][1] + sred[tid][2][1] + sred[tid][3][1];
        float ez  = __expf(ent * wconst * INVT);
        float Z   = esum + ez;
        float iz  = 1.0f / Z;
        invZ[tid] = iz;
        entP[tid] = ez * iz;
    }
    __syncthreads();

    // sweep 3: normalized probs -> LDS (pad cols select 0; covers cols 784..831)
    float izl[4];
    #pragma unroll
    for (int j = 0; j < 4; ++j) izl[j] = invZ[g * 4 + j];
    #pragma unroll
    for (int tt = 0; tt < 13; ++tt) {
        int gt = w * 13 + tt;
        int col = gt * 16 + lr;
        #pragma unroll
        for (int j = 0; j < 4; ++j) {
            float v = acc[tt][j] * izl[j];
            if (gt >= 49) v = 0.f;
            otile[g * 4 + j][col] = f2bf(v);
        }
    }
    __syncthreads();
    if (tid < 16) otile[tid][784] = f2bf(entP[tid]);
    __syncthreads();

    for (int v = tid; v < 16 * 104; v += 256) {
        int row = v / 104, cv = v % 104;
        *(u16x8*)(OUT + (size_t)(r0 + row) * Pp + cv * 8) = *(const u16x8*)(&otile[row][cv * 8]);
    }
}

// ---------------- K3: dust rows (row 784) + zero pad rows ----------------
__global__ __launch_bounds__(256) void k_dustrow(const float* __restrict__ cs12,
                                                 const float* __restrict__ cs21,
                                                 unsigned short* __restrict__ P12h,
                                                 unsigned short* __restrict__ P21h)
{
    constexpr float INVT = 1.0f / TEMP;
    const size_t MMp = (size_t)Pp * Pp;
    int bt = blockIdx.x, side = blockIdx.y;
    const float* cs = (side ? cs21 : cs12) + (size_t)bt * Pp;
    unsigned short* OUT = (side ? P21h : P12h) + (size_t)bt * MMp;
    __shared__ float sbuf[4];
    int tid = threadIdx.x;
    float v[4];
    #pragma unroll
    for (int k = 0; k < 4; ++k) {
        int j = tid + k * 256;
        float val = -INFINITY;
        if (j < Nc)       val = -cs[j] * INVT;
        else if (j == Nc) val = 0.f;
        v[k] = val;
    }
    float mx = fmaxf(fmaxf(v[0], v[1]), fmaxf(v[2], v[3]));
    mx = blockReduceMax(mx, sbuf);
    float e[4]; float s = 0.f;
    #pragma unroll
    for (int k = 0; k < 4; ++k) {
        int j = tid + k * 256;
        e[k] = (j < Mc) ? __expf(v[k] - mx) : 0.f;
        s += e[k];
    }
    s = blockReduceSum(s, sbuf);
    float invs = 1.f / s;
    #pragma unroll
    for (int k = 0; k < 4; ++k) {
        int j = tid + k * 256;
        if (j < Mc)      OUT[(size_t)Nc * Pp + j] = f2bf(e[k] * invs);
        else if (j < Pp) OUT[(size_t)Nc * Pp + j] = 0;
    }
    u16x8 z = {};
    u16x8* dst = (u16x8*)(OUT + (size_t)785 * Pp);
    for (int i = tid; i < (Pp - 785) * Pp / 8; i += 256) dst[i] = z;
}

// ---------------- K6: merged bf16 transposes (grid z = 0..27) ----------------
__global__ __launch_bounds__(256) void k_transpose_bf16(const unsigned short* __restrict__ P12h,
                                                        const unsigned short* __restrict__ P21h,
                                                        unsigned short* __restrict__ Db)
{
    const size_t MMp = (size_t)Pp * Pp;
    __shared__ unsigned short tile[64][65];
    int z = blockIdx.z;
    const unsigned short* S;
    if (z < 24) { int b = z / 6, tm = z % 6; S = P12h + ((size_t)b * 7 + tm + 1) * MMp; }
    else        { S = P21h + ((size_t)(z - 24) * 7 + 6) * MMp; }
    unsigned short* D = Db + (size_t)z * MMp;
    int x0 = blockIdx.x * 64, y0 = blockIdx.y * 64;
    int tx = threadIdx.x & 63, ty = threadIdx.x >> 6;
    #pragma unroll
    for (int y = 0; y < 64; y += 4) tile[y + ty][tx] = S[(size_t)(y0 + y + ty) * Pp + x0 + tx];
    __syncthreads();
    #pragma unroll
    for (int y = 0; y < 64; y += 4) D[(size_t)(x0 + y + ty) * Pp + y0 + tx] = tile[tx][y + ty];
}

// ---------------- K7: fused chain GEMM (64x128 db tiles) + loss ----------------
struct GJobs {
    const unsigned short* A[2];
    const unsigned short* BT[2];
    unsigned short* Cb[2];
    float* cs[2];
    long long sA[2], sB[2], sC[2];
    const unsigned short* Lr;
    const unsigned short* Rr;
    const float* csL;
    float* loss;
    float scale;
};

__global__ __launch_bounds__(256, 3) void k_gemm_loss(GJobs J)
{
    const size_t MMp = (size_t)Pp * Pp;
    if (blockIdx.x >= 728) {
        int q = blockIdx.x - 728;
        int w = threadIdx.x >> 6, lane = threadIdx.x & 63;
        int r = q * 4 + w;
        int b = r / Mc, i = r % Mc;
        const u16x8* lrow = (const u16x8*)(J.Lr + (size_t)b * MMp + (size_t)i * Pp);
        const u16x8* rrow = (const u16x8*)(J.Rr + (size_t)b * MMp + (size_t)i * Pp);
        const f32x4* cs4  = (const f32x4*)(J.csL + (size_t)b * Pp);
        float sR = 0.f, sD = 0.f;
        for (int c = lane; c < Pp / 8; c += 64) {
            u16x8 lv = lrow[c];
            u16x8 rv = rrow[c];
            f32x4 c0 = cs4[2 * c], c1 = cs4[2 * c + 1];
            #pragma unroll
            for (int k = 0; k < 4; ++k) {
                float fl = bf2f(lv[k]);
                sR += fl * c0[k];
                sD += fl * bf2f(rv[k]);
            }
            #pragma unroll
            for (int k = 0; k < 4; ++k) {
                float fl = bf2f(lv[4 + k]);
                sR += fl * c1[k];
                sD += fl * bf2f(rv[4 + k]);
            }
        }
        #pragma unroll
        for (int off = 1; off <= 32; off <<= 1) {
            sR += __shfl_xor(sR, off, 64);
            sD += __shfl_xor(sD, off, 64);
        }
        if (lane == 0)
            atomicAdd(J.loss, (logf(sR + Mc * 1e-20f) - logf(sD + 1e-20f)) * J.scale);
        return;
    }

    __shared__ __align__(16) unsigned short As0[64 * 64], As1[64 * 64];
    __shared__ __align__(16) unsigned short Bs0[128 * 64], Bs1[128 * 64];

    int f = blockIdx.x;
    int zz = f & 7, slot = f >> 3;
    int job = zz >> 2, b = zz & 3;
    const unsigned short* A  = J.A[job]  + (size_t)b * J.sA[job];
    const unsigned short* BT = J.BT[job] + (size_t)b * J.sB[job];

    const int i0 = (slot / 7) * 64, j0 = (slot % 7) * 128;
    const int tid = threadIdx.x, lane = tid & 63, wv = tid >> 6;
    const int g = lane >> 4, lr = lane & 15;

    f32x4 acc[4][2] = {};
    gemm64x128_db<Pp>(A, BT, As0, As1, Bs0, Bs1, i0, j0, tid, acc);

    unsigned short* Co = J.Cb[job] + (size_t)b * J.sC[job];
    float* csp = J.cs[job];
    float csacc[2] = {0.f, 0.f};
    #pragma unroll
    for (int m = 0; m < 4; ++m)
        #pragma unroll
        for (int n = 0; n < 2; ++n)
            #pragma unroll
            for (int j = 0; j < 4; ++j) {
                int row = i0 + m * 16 + g * 4 + j;
                int col = j0 + wv * 32 + n * 16 + lr;
                if (col < Pp) {
                    unsigned short h = f2bf(acc[m][n][j]);
                    Co[(size_t)row * Pp + col] = h;
                    csacc[n] += bf2f(h);
                }
            }
    if (csp) {
        csp += (size_t)b * Pp;
        #pragma unroll
        for (int n = 0; n < 2; ++n) {
            float p = csacc[n];
            p += __shfl_xor(p, 16, 64);
            p += __shfl_xor(p, 32, 64);
            int col = j0 + wv * 32 + n * 16 + lr;
            if (g == 0 && col < Pp) atomicAdd(&csp[col], p);
        }
    }
}

// ---------------- K8: standalone loss rows (final step) ----------------
__global__ __launch_bounds__(64) void k_lossrow(const unsigned short* __restrict__ L,
                                                const unsigned short* __restrict__ R,
                                                const float* __restrict__ csR,
                                                float* __restrict__ loss, float scale)
{
    const size_t MMp = (size_t)Pp * Pp;
    int r = blockIdx.x;
    int b = r / Mc, i = r % Mc;
    const u16x8* lrow = (const u16x8*)(L + (size_t)b * MMp + (size_t)i * Pp);
    const u16x8* rrow = (const u16x8*)(R + (size_t)b * MMp + (size_t)i * Pp);
    const f32x4* cs4  = (const f32x4*)(csR + (size_t)b * Pp);
    int lane = threadIdx.x;
    float sR = 0.f, sD = 0.f;
    for (int c = lane; c < Pp / 8; c += 64) {
        u16x8 lv = lrow[c];
        u16x8 rv = rrow[c];
        f32x4 c0 = cs4[2 * c], c1 = cs4[2 * c + 1];
        #pragma unroll
        for (int k = 0; k < 4; ++k) {
            float fl = bf2f(lv[k]);
            sR += fl * c0[k];
            sD += fl * bf2f(rv[k]);
        }
        #pragma unroll
        for (int k = 0; k < 4; ++k) {
            float fl = bf2f(lv[4 + k]);
            sR += fl * c1[k];
            sD += fl * bf2f(rv[4 + k]);
        }
    }
    #pragma unroll
    for (int off = 1; off <= 32; off <<= 1) {
        sR += __shfl_xor(sR, off, 64);
        sD += __shfl_xor(sD, off, 64);
    }
    if (lane == 0)
        atomicAdd(loss, (logf(sR + Mc * 1e-20f) - logf(sD + 1e-20f)) * scale);
}

// ---------------- host orchestration ----------------
extern "C" void kernel_launch(void* const* d_in, const int* in_sizes, int n_in,
                              void* d_out, int out_size, void* d_ws, size_t ws_size,
                              hipStream_t stream)
{
    const float* feats = (const float*)d_in[0];
    const float* dust  = (const float*)d_in[1];
    const float* Wself = (const float*)d_in[2];
    const float* bself = (const float*)d_in[3];
    const float* Wdust = (const float*)d_in[4];
    const float* bdust = (const float*)d_in[5];

    float* out  = (float*)d_out;
    float* qout = out;
    float* loss = out + (size_t)Bc * Dc * Tc * Mc;

    const size_t MMp = (size_t)Pp * Pp;       // 692,224

    // ---- workspace ----
    float* ws = (float*)d_ws;
    float* csR = ws;                                                // 6 slots * Bc * Pp fp32
    unsigned short* P12h = (unsigned short*)(ws + 4 * MMp);         // 28*MMp bf16
    unsigned short* P21h = P12h + (size_t)28 * MMp;                 // 28*MMp bf16
    unsigned short* chainT = P21h + (size_t)28 * MMp;               // 44*MMp bf16 region
    unsigned short* P12T  = chainT;
    unsigned short* P21T6 = P12T + (size_t)24 * MMp;
    unsigned short* l0    = P21T6 + (size_t)4 * MMp;
    unsigned short* l1    = l0 + (size_t)4 * MMp;
    unsigned short* R0    = l1 + (size_t)4 * MMp;
    unsigned short* R1    = R0 + (size_t)4 * MMp;
    unsigned short* qTb   = R1 + (size_t)4 * MMp;                   // 32*Qrows*Dc bf16
    float* cs12 = (float*)(qTb + (size_t)32 * Qrows * Dc);          // 28*Pp fp32
    float* cs21 = cs12 + (size_t)28 * Pp;                           // 28*Pp fp32

    // phase-1 overlays in chainT region:
    unsigned short* Abf   = chainT;
    unsigned int*   Abf32 = (unsigned int*)Abf;
    unsigned short* WTb   = Abf + (size_t)Bc * Tc * Nc * Cc;
    float*          fbuf  = (float*)(WTb + 2 * (size_t)Dc * Cc);

    // 1. pack inputs (+W pack +zero roles incl. qTb pad rows)
    k_pack<<<Bc * Nc + 32 + 8, 256, 0, stream>>>(feats, Wself, Wdust, Abf32, WTb, qTb, csR, loss);
    // 2. projection GEMM + bias (64x128 tiles)
    k_gemm_proj<<<392, 256, 0, stream>>>(Abf, WTb, bself, fbuf);
    // 3. norms (+dust projection role; qTb row 784 stays zero)
    k_norm<<<dim3(14, 32), 256, 0, stream>>>(fbuf, dust, Wdust, bdust, qTb, qout);
    // 4. fused affinity (guard-free), then dust rows
    float wconst = (float)(1.0 / log(784.0));
    k_affinity<<<2744, 256, 0, stream>>>(qTb, P12h, P21h, cs12, cs21, wconst);
    k_dustrow<<<dim3(28, 2), 256, 0, stream>>>(cs12, cs21, P12h, P21h);
    // 5. merged bf16 transposes
    k_transpose_bf16<<<dim3(13, 13, 28), 256, 0, stream>>>(P12h, P21h, P12T);

    // 6. chain
    const float scale = 1.0f / (6.0f * Bc * Mc);

    {
        GJobs J = {};
        J.A[0] = P12h;  J.sA[0] = (long long)7 * MMp;
        J.BT[0] = P12T; J.sB[0] = (long long)6 * MMp;
        J.Cb[0] = l0;   J.sC[0] = (long long)MMp; J.cs[0] = nullptr;
        J.A[1] = P21T6;                   J.sA[1] = (long long)MMp;
        J.BT[1] = P21h + (size_t)5 * MMp; J.sB[1] = (long long)7 * MMp;
        J.Cb[1] = R0;   J.sC[1] = (long long)MMp; J.cs[1] = csR;   // slot 0
        k_gemm_loss<<<728, 256, 0, stream>>>(J);
    }

    unsigned short *lcur = l0, *lnxt = l1, *rcur = R0, *rnxt = R1;
    for (int i = 1; i <= 5; ++i) {
        GJobs J = {};
        J.A[0] = lcur; J.sA[0] = (long long)MMp;
        J.BT[0] = P12T + (size_t)i * MMp; J.sB[0] = (long long)6 * MMp;
        J.Cb[0] = lnxt; J.sC[0] = (long long)MMp; J.cs[0] = nullptr;
        J.A[1] = rcur; J.sA[1] = (long long)MMp;
        J.BT[1] = P21h + (size_t)(5 - i) * MMp; J.sB[1] = (long long)7 * MMp;
        J.Cb[1] = rnxt; J.sC[1] = (long long)MMp; J.cs[1] = csR + (size_t)i * Bc * Pp;
        J.Lr = lcur; J.Rr = rcur; J.csL = csR + (size_t)(i - 1) * Bc * Pp;
        J.loss = loss; J.scale = scale;
        k_gemm_loss<<<728 + 785, 256, 0, stream>>>(J);
        unsigned short* t;
        t = lcur; lcur = lnxt; lnxt = t;
        t = rcur; rcur = rnxt; rnxt = t;
    }
    // final loss (state 6)
    k_lossrow<<<Bc * Mc, 64, 0, stream>>>(lcur, rcur, csR + (size_t)5 * Bc * Pp, loss, scale);
}